// Round 9
// baseline (229.771 us; speedup 1.0000x reference)
//
#include <hip/hip_runtime.h>

#define IN_FEATS 256
#define OUT_FEATS 32
#define NUM_HEADS 4
#define NHF 128   // NUM_HEADS*OUT_FEATS

#define NCH 512   // edge chunks for hist/bin (chunk<=1792 for E<=917504)

typedef __attribute__((ext_vector_type(8))) short short8;
typedef __attribute__((ext_vector_type(4))) float f32x4;

__device__ inline unsigned short f2bf(float f) {
    unsigned int u = __builtin_bit_cast(unsigned int, f);
    u = (u + 0x7fff + ((u >> 16) & 1)) >> 16;   // RNE
    return (unsigned short)u;
}
__device__ inline float bfhi2f(unsigned int packed_hi) {   // bits already in [31:16]
    return __builtin_bit_cast(float, packed_hi);
}

// prep_hist: blocks 0..127 transpose W -> Wt bf16 [128][256]; block 128 computes
// v[k*4+h]; blocks 129..129+NCH-1 write per-chunk partial histograms (full
// overwrite -> no zero-init needed anywhere).
__global__ __launch_bounds__(256) void prep_hist(const float* __restrict__ W,
                                                 const float* __restrict__ attn_r,
                                                 const int* __restrict__ dst,
                                                 float* __restrict__ v,
                                                 unsigned short* __restrict__ Wt,
                                                 int* __restrict__ partial,
                                                 int E) {
    const int t = threadIdx.x;
    const int b = blockIdx.x;
    if (b < 128) {
        Wt[b * 256 + t] = f2bf(W[(size_t)t * NHF + b]);
    } else if (b == 128) {
        for (int p = t; p < IN_FEATS * NUM_HEADS; p += 256) {
            int k = p >> 2, h = p & 3;
            const float* wr = W + (size_t)k * NHF + h * OUT_FEATS;
            const float* ar = attn_r + h * OUT_FEATS;
            float s = 0.f;
            #pragma unroll
            for (int f = 0; f < OUT_FEATS; ++f) s += wr[f] * ar[f];
            v[p] = s;
        }
    } else {
        __shared__ int cnt[256];
        const int hb = b - 129;
        const int chunk = (E + NCH - 1) / NCH;
        const int e0 = hb * chunk;
        const int e1 = min(e0 + chunk, E);
        cnt[t] = 0;
        __syncthreads();
        for (int e = e0 + t; e < e1; e += 256)
            atomicAdd(&cnt[dst[e] >> 8], 1);
        __syncthreads();
        partial[hb * 256 + t] = cnt[t];
    }
}

// bin_gemm v3: roles INTERLEAVED (odd blockIdx < 2*NCH -> bin, even -> gemm,
// rest -> gemm). Every CU holds ~1 gemm + ~1 bin block concurrently, so bin's
// L2-sweep/scatter latency hides under gemm's MFMA instead of forming a
// latency-only tail (R8: gemm-first = 48us; R7: bin-first = 69us).
#define BSTRIDE 136   // bf16 elems; 272 B rows: 16B-aligned, 4-bank shift/row
__global__ __launch_bounds__(256) void bin_gemm(const int* __restrict__ src,
                                                const int* __restrict__ dst,
                                                const int* __restrict__ partial,
                                                unsigned int* __restrict__ pairs,
                                                int* __restrict__ bbase,
                                                int E,
                                                const float* __restrict__ A,
                                                const unsigned short* __restrict__ Wt,
                                                const float* __restrict__ attn_l,
                                                unsigned short* __restrict__ ft16,
                                                float* __restrict__ el, int M,
                                                int ngb) {
    __shared__ unsigned short WtL[128 * 256];   // 64 KB (bin aliases 3 KB of it)

    // ---- role interleave ----
    const int i = blockIdx.x;
    int role_bin, bidx = 0, gidx = 0;
    if (ngb >= NCH) {
        if (i < 2 * NCH) { role_bin = (i & 1); bidx = i >> 1; gidx = i >> 1; }
        else             { role_bin = 0; gidx = i - NCH; }
    } else {
        if (i < 2 * ngb) { role_bin = (i & 1); bidx = i >> 1; gidx = i >> 1; }
        else             { role_bin = 1; bidx = i - ngb; }
    }

    if (role_bin) {
        // ---------------- bin ----------------
        int* sc    = (int*)WtL;          // [0..255]
        int* basel = (int*)WtL + 256;    // [256..511]
        int* cnt   = (int*)WtL + 512;    // [512..767]
        const int t = threadIdx.x;
        const int b = bidx;
        const int chunk = (E + NCH - 1) / NCH;
        const int e0 = b * chunk;
        const int e1 = min(e0 + chunk, E);

        // preload this block's edges (static reg indices, predicated)
        int dreg[7], sreg[7];
        #pragma unroll
        for (int ii = 0; ii < 7; ++ii) {
            const int e = e0 + t + ii * 256;
            const bool ok = e < e1;
            dreg[ii] = ok ? dst[e] : 0;
            sreg[ii] = ok ? src[e] : 0;
        }

        // base derivation: colsum over all rows, rowpref over rows < b
        int colsum = 0, rowpref = 0;
        {
            int bb = 0;
            #pragma unroll 8
            for (; bb < b; ++bb) {
                const int pv = partial[bb * 256 + t];
                colsum += pv;
                rowpref += pv;
            }
            #pragma unroll 8
            for (; bb < NCH; ++bb) colsum += partial[bb * 256 + t];
        }
        sc[t] = colsum;
        __syncthreads();
        #pragma unroll
        for (int d = 1; d < 256; d <<= 1) {
            int x = (t >= d) ? sc[t - d] : 0;
            __syncthreads();
            sc[t] += x;
            __syncthreads();
        }
        if (b == 0) {
            bbase[t] = sc[t] - colsum;
            if (t == 255) bbase[256] = sc[255];
        }
        basel[t] = (sc[t] - colsum) + rowpref;
        cnt[t] = 0;
        __syncthreads();

        // scatter (only LDS-atomic latency on the chain)
        #pragma unroll
        for (int ii = 0; ii < 7; ++ii) {
            const int e = e0 + t + ii * 256;
            if (e < e1) {
                const int d = dreg[ii];
                const int bk = d >> 8;
                const int o = atomicAdd(&cnt[bk], 1);
                pairs[basel[bk] + o] = (unsigned int)sreg[ii] | ((unsigned int)(d & 255) << 16);
            }
        }
        for (int e = e0 + t + 7 * 256; e < e1; e += 256) {   // tail (empty for E<=917504)
            const int d = dst[e];
            const int bk = d >> 8;
            const int o = atomicAdd(&cnt[bk], 1);
            pairs[basel[bk] + o] = (unsigned int)src[e] | ((unsigned int)(d & 255) << 16);
        }
        return;
    }

    // ---------------- gemm_el ----------------
    const int gb   = gidx;
    const int wave = threadIdx.x >> 6;
    const int lane = threadIdx.x & 63;
    const int quad = lane >> 4;
    const int mc   = lane & 15;
    const int row_base = gb * 64 + wave * 16;

    for (int ii = threadIdx.x; ii < 4096; ii += 256) {
        const int n = ii >> 5, c = ii & 31;
        const int cs = (c + n) & 31;
        *(uint4*)(WtL + n * 256 + cs * 8) = *(const uint4*)(Wt + n * 256 + c * 8);
    }

    float al[8];
    #pragma unroll
    for (int t = 0; t < 8; ++t) al[t] = attn_l[(t >> 1) * 32 + (t & 1) * 16 + mc];

    const int rowA = min(row_base + mc, M - 1);
    const float* arow = A + (size_t)rowA * IN_FEATS;

    float4 a[8][2];
    #pragma unroll
    for (int kk = 0; kk < 8; ++kk) {
        a[kk][0] = *(const float4*)(arow + kk * 32 + quad * 8);
        a[kk][1] = *(const float4*)(arow + kk * 32 + quad * 8 + 4);
    }

    f32x4 acc[8];
    #pragma unroll
    for (int t = 0; t < 8; ++t) acc[t] = (f32x4){0.f, 0.f, 0.f, 0.f};

    __syncthreads();

    #pragma unroll
    for (int kk = 0; kk < 8; ++kk) {
        short8 af;
        af[0] = (short)f2bf(a[kk][0].x); af[1] = (short)f2bf(a[kk][0].y);
        af[2] = (short)f2bf(a[kk][0].z); af[3] = (short)f2bf(a[kk][0].w);
        af[4] = (short)f2bf(a[kk][1].x); af[5] = (short)f2bf(a[kk][1].y);
        af[6] = (short)f2bf(a[kk][1].z); af[7] = (short)f2bf(a[kk][1].w);
        #pragma unroll
        for (int t = 0; t < 8; ++t) {
            const int n = t * 16 + mc;
            const int c = ((kk << 2) + quad + n) & 31;
            const short8 bf = *(const short8*)(WtL + n * 256 + c * 8);
            acc[t] = __builtin_amdgcn_mfma_f32_16x16x32_bf16(af, bf, acc[t], 0, 0, 0);
        }
    }

    float elp[4][4];
    #pragma unroll
    for (int v = 0; v < 4; ++v)
        #pragma unroll
        for (int h = 0; h < 4; ++h) elp[v][h] = 0.f;
    #pragma unroll
    for (int v = 0; v < 4; ++v)
        #pragma unroll
        for (int t = 0; t < 8; ++t) elp[v][t >> 1] += acc[t][v] * al[t];
    #pragma unroll
    for (int v = 0; v < 4; ++v)
        #pragma unroll
        for (int h = 0; h < 4; ++h) {
            #pragma unroll
            for (int d = 1; d < 16; d <<= 1)
                elp[v][h] += __shfl_xor(elp[v][h], d, 64);
        }

    // el store (registers only, before LDS reuse)
    #pragma unroll
    for (int v = 0; v < 4; ++v) {
        const int rg = row_base + quad * 4 + v;
        if (rg < M && mc < 4) {
            float ev = (mc == 0) ? elp[v][0] : (mc == 1) ? elp[v][1]
                     : (mc == 2) ? elp[v][2] : elp[v][3];
            el[(size_t)rg * 4 + mc] = ev;
        }
    }

    __syncthreads();   // all waves done reading WtL -> safe to reuse as bounce
    #pragma unroll
    for (int v = 0; v < 4; ++v) {
        const int lr = wave * 16 + quad * 4 + v;
        #pragma unroll
        for (int t = 0; t < 8; ++t)
            WtL[lr * BSTRIDE + t * 16 + mc] = f2bf(acc[t][v]);
    }
    __syncthreads();
    const int rows_in_blk = min(64, M - gb * 64);
    for (int ii = threadIdx.x; ii < 64 * 16; ii += 256) {   // 16B segs
        const int lr = ii >> 4, seg = ii & 15;
        if (lr < rows_in_blk)
            *(uint4*)(ft16 + (size_t)(gb * 64 + lr) * NHF + seg * 8) =
                *(const uint4*)(WtL + lr * BSTRIDE + seg * 8);
    }
}

// er_fine: blocks 0..nb-1 = fine CSR per bucket (2KB LDS, cheap); blocks nb..
// = compute_er (one wave per dst row, no LDS). csr stored as u16 (src<65536).
__global__ __launch_bounds__(256) void er_fine(const float* __restrict__ hdst,
                                               const float* __restrict__ v,
                                               float* __restrict__ er, int M,
                                               const unsigned int* __restrict__ pairs,
                                               const int* __restrict__ bbase,
                                               int* __restrict__ off,
                                               unsigned short* __restrict__ csr16,
                                               int nb, int n_dst, int E) {
    __shared__ int cnt[256];
    __shared__ int cur[256];

    if (blockIdx.x < (unsigned)nb) {
        const int t = threadIdx.x;
        const int b = blockIdx.x;
        const int p0 = bbase[b], p1 = bbase[b + 1];
        cnt[t] = 0;
        __syncthreads();
        for (int p = p0 + t; p < p1; p += 256)
            atomicAdd(&cnt[pairs[p] >> 16], 1);
        __syncthreads();
        int vv = cnt[t];
        cur[t] = vv;
        __syncthreads();
        #pragma unroll
        for (int d = 1; d < 256; d <<= 1) {
            int x = (t >= d) ? cur[t - d] : 0;
            __syncthreads();
            cur[t] += x;
            __syncthreads();
        }
        int ex = cur[t] - vv;
        int node = b * 256 + t;
        if (node < n_dst) off[node] = p0 + ex;
        if (b == 0 && t == 0) off[n_dst] = E;
        __syncthreads();
        cur[t] = ex;
        __syncthreads();
        for (int p = p0 + t; p < p1; p += 256) {
            unsigned int pr = pairs[p];
            int o = atomicAdd(&cur[pr >> 16], 1);
            csr16[p0 + o] = (unsigned short)(pr & 0xffffu);
        }
        return;
    }

    // ---- compute_er ----
    int wid  = ((blockIdx.x - nb) * 256 + threadIdx.x) >> 6;
    int lane = threadIdx.x & 63;
    if (wid >= M) return;
    const float4 x = *(const float4*)(hdst + (size_t)wid * IN_FEATS + lane * 4);
    const float4* vp = (const float4*)(v + (size_t)lane * 16);
    float4 v0 = vp[0], v1 = vp[1], v2 = vp[2], v3 = vp[3];
    float a0 = x.x * v0.x + x.y * v1.x + x.z * v2.x + x.w * v3.x;
    float a1 = x.x * v0.y + x.y * v1.y + x.z * v2.y + x.w * v3.y;
    float a2 = x.x * v0.z + x.y * v1.z + x.z * v2.z + x.w * v3.z;
    float a3 = x.x * v0.w + x.y * v1.w + x.z * v2.w + x.w * v3.w;
    #pragma unroll
    for (int m = 32; m >= 1; m >>= 1) {
        a0 += __shfl_xor(a0, m, 64);
        a1 += __shfl_xor(a1, m, 64);
        a2 += __shfl_xor(a2, m, 64);
        a3 += __shfl_xor(a3, m, 64);
    }
    if (lane == 0) *(float4*)(er + (size_t)wid * 4) = make_float4(a0, a1, a2, a3);
}

// TWO dst nodes per wave (32 lanes each; lane owns cols 4*hl..4*hl+3).
// Per half-wave: up to 32 csr entries preloaded with ONE coalesced u16 load,
// broadcast via __shfl(width=32). 8-edge chunks, 2-stage software pipeline.
__global__ __launch_bounds__(256) void agg_pull(const int* __restrict__ off,
                                                const unsigned short* __restrict__ csr16,
                                                const float* __restrict__ el,
                                                const float* __restrict__ er,
                                                const uint2* __restrict__ ftp,
                                                float* __restrict__ out, int n_dst) {
    const int wid  = (blockIdx.x * blockDim.x + threadIdx.x) >> 6;
    const int lane = threadIdx.x & 63;
    const int half = lane >> 5;
    const int hl   = lane & 31;
    const int node = wid * 2 + half;
    const bool valid = node < n_dst;
    const int nc = valid ? node : 0;
    const int h  = hl >> 3;                       // head = (4*hl)/32
    const float er_h = er[nc * 4 + h];
    const int start = off[nc];
    const int end   = valid ? off[nc + 1] : start;
    const int deg   = end - start;
    const int last  = max(end - 1, 0);

    const int sl = (int)csr16[min(start + hl, last)];

    const int mdeg  = max(deg, __shfl_xor(deg, 32, 64));
    const int iters = (min(mdeg, 32) + 7) >> 3;

    float a0 = 0.f, a1 = 0.f, a2 = 0.f, a3 = 0.f, sw = 0.f;

    float e[8]; uint2 q[8];
    #pragma unroll
    for (int j = 0; j < 8; ++j) {
        const int s = __shfl(sl, j, 32);
        e[j] = el[s * 4 + h];
        q[j] = ftp[s * 32 + hl];
    }

    for (int i = 0; i < iters; ++i) {
        float f[8]; uint2 r[8];
        const int jn = (i + 1) << 3;
        #pragma unroll
        for (int j = 0; j < 8; ++j) {
            const int s = __shfl(sl, min(jn + j, 31), 32);
            f[j] = el[s * 4 + h];
            r[j] = ftp[s * 32 + hl];
        }

        const int kb = start + (i << 3);
        #pragma unroll
        for (int j = 0; j < 8; ++j) {
            float x = e[j] + er_h;
            x = fmaxf(x, 0.2f * x);
            const float w = (kb + j < end) ? __expf(x) : 0.f;
            sw += w;
            a0 = fmaf(bfhi2f(q[j].x << 16),          w, a0);
            a1 = fmaf(bfhi2f(q[j].x & 0xffff0000u),  w, a1);
            a2 = fmaf(bfhi2f(q[j].y << 16),          w, a2);
            a3 = fmaf(bfhi2f(q[j].y & 0xffff0000u),  w, a3);
        }

        #pragma unroll
        for (int j = 0; j < 8; ++j) { e[j] = f[j]; q[j] = r[j]; }
    }

    for (int k = start + 32; k < end; ++k) {
        const int s = (int)csr16[k];
        float x = el[s * 4 + h] + er_h;
        x = fmaxf(x, 0.2f * x);
        const float w = __expf(x);
        const uint2 qq = ftp[s * 32 + hl];
        sw += w;
        a0 = fmaf(bfhi2f(qq.x << 16),         w, a0);
        a1 = fmaf(bfhi2f(qq.x & 0xffff0000u), w, a1);
        a2 = fmaf(bfhi2f(qq.y << 16),         w, a2);
        a3 = fmaf(bfhi2f(qq.y & 0xffff0000u), w, a3);
    }

    if (valid) {
        const float inv = (deg > 0) ? 1.f / sw : 0.f;
        float4 r;
        r.x = a0 * inv; r.y = a1 * inv; r.z = a2 * inv; r.w = a3 * inv;
        *(float4*)(out + (size_t)node * NHF + hl * 4) = r;
    }
}

extern "C" void kernel_launch(void* const* d_in, const int* in_sizes, int n_in,
                              void* d_out, int out_size, void* d_ws, size_t ws_size,
                              hipStream_t stream) {
    const float* h_src  = (const float*)d_in[0];
    const float* h_dst  = (const float*)d_in[1];
    const float* W      = (const float*)d_in[2];
    const float* attn_l = (const float*)d_in[3];
    const float* attn_r = (const float*)d_in[4];
    const int* src_idx  = (const int*)d_in[5];
    const int* dst_idx  = (const int*)d_in[6];

    const int n_src = in_sizes[0] / IN_FEATS;   // 50000
    const int n_dst = in_sizes[1] / IN_FEATS;   // 50000
    const int E     = in_sizes[5];              // 800000

    const int nb = (n_dst + 255) >> 8;          // 196 buckets (<=256)

    // workspace layout
    char* ws = (char*)d_ws;
    size_t o = 0;
    float* v       = (float*)(ws + o); o += 4096;
    float* el      = (float*)(ws + o); o += (size_t)n_src * 4 * sizeof(float);
    float* er      = (float*)(ws + o); o += (size_t)n_dst * 4 * sizeof(float);
    int*   off     = (int*)(ws + o);   o += ((size_t)n_dst + 16) * sizeof(int);
    int*   bbase   = (int*)(ws + o);   o += 260 * sizeof(int);
    int*   partial = (int*)(ws + o);   o += (size_t)NCH * 256 * sizeof(int);
    unsigned short* Wt = (unsigned short*)(ws + o); o += (size_t)NHF * IN_FEATS * sizeof(unsigned short);
    unsigned short* csr16 = (unsigned short*)(ws + o); o += (((size_t)E * 2 + 15) & ~15ull);
    unsigned int* pairs = (unsigned int*)(ws + o); o += (size_t)E * sizeof(unsigned int);
    unsigned short* ft16 = (unsigned short*)(ws + o); o += (size_t)n_src * NHF * sizeof(unsigned short);

    float* out = (float*)d_out;

    const int ngb = (n_src + 63) / 64;

    prep_hist<<<129 + NCH, 256, 0, stream>>>(W, attn_r, dst_idx, v, Wt, partial, E);
    bin_gemm<<<ngb + NCH, 256, 0, stream>>>(src_idx, dst_idx, partial,
                                            pairs, bbase, E,
                                            h_src, Wt, attn_l, ft16, el, n_src, ngb);
    {
        const int er_blocks = (n_dst * 64 + 255) / 256;  // 4 rows/block
        er_fine<<<nb + er_blocks, 256, 0, stream>>>(h_dst, v, er, n_dst, pairs,
                                                    bbase, off, csr16, nb, n_dst, E);
    }
    {
        const int nwave = (n_dst + 1) >> 1;          // 2 nodes per wave
        agg_pull<<<(nwave + 3) / 4, 256, 0, stream>>>(off, csr16, el, er,
                                                      (const uint2*)ft16, out, n_dst);
    }
}

// Round 10
// 219.277 us; speedup vs baseline: 1.0479x; 1.0479x over previous
//
#include <hip/hip_runtime.h>

#define IN_FEATS 256
#define OUT_FEATS 32
#define NUM_HEADS 4
#define NHF 128   // NUM_HEADS*OUT_FEATS

#define NCH 256   // edge chunks for hist/bin; chunk<=3328 covered by 13-reg preload
#define PRE 13    // preload regs: PRE*256 >= chunk

typedef __attribute__((ext_vector_type(8))) short short8;
typedef __attribute__((ext_vector_type(4))) float f32x4;

__device__ inline unsigned short f2bf(float f) {
    unsigned int u = __builtin_bit_cast(unsigned int, f);
    u = (u + 0x7fff + ((u >> 16) & 1)) >> 16;   // RNE
    return (unsigned short)u;
}
__device__ inline float bfhi2f(unsigned int packed_hi) {   // bits already in [31:16]
    return __builtin_bit_cast(float, packed_hi);
}

// prep_hist: blocks 0..127 transpose W -> Wt bf16 [128][256]; block 128 computes
// v[k*4+h]; blocks 129..129+NCH-1 write per-chunk partial histograms (full
// overwrite -> no zero-init needed anywhere).
__global__ __launch_bounds__(256) void prep_hist(const float* __restrict__ W,
                                                 const float* __restrict__ attn_r,
                                                 const int* __restrict__ dst,
                                                 float* __restrict__ v,
                                                 unsigned short* __restrict__ Wt,
                                                 int* __restrict__ partial,
                                                 int E) {
    const int t = threadIdx.x;
    const int b = blockIdx.x;
    if (b < 128) {
        Wt[b * 256 + t] = f2bf(W[(size_t)t * NHF + b]);
    } else if (b == 128) {
        for (int p = t; p < IN_FEATS * NUM_HEADS; p += 256) {
            int k = p >> 2, h = p & 3;
            const float* wr = W + (size_t)k * NHF + h * OUT_FEATS;
            const float* ar = attn_r + h * OUT_FEATS;
            float s = 0.f;
            #pragma unroll
            for (int f = 0; f < OUT_FEATS; ++f) s += wr[f] * ar[f];
            v[p] = s;
        }
    } else {
        __shared__ int cnt[256];
        const int hb = b - 129;
        const int chunk = (E + NCH - 1) / NCH;
        const int e0 = hb * chunk;
        const int e1 = min(e0 + chunk, E);
        cnt[t] = 0;
        __syncthreads();
        for (int e = e0 + t; e < e1; e += 256)
            atomicAdd(&cnt[dst[e] >> 8], 1);
        __syncthreads();
        partial[hb * 256 + t] = cnt[t];
    }
}

// bin_gemm (R8 ordering: gemm blocks FIRST, bin behind) with NCH=256: the bin
// partial-sweep is 2x shorter per block and 4x less total L2 traffic
// (NCH^2 scaling: 256MB -> 64MB). Interleaved roles (R9) regressed: under the
// 2-blocks/CU LDS cap, a {gemm+bin} CU has less gemm throughput than {gemm,gemm}.
#define BSTRIDE 136   // bf16 elems; 272 B rows: 16B-aligned, 4-bank shift/row
__global__ __launch_bounds__(256) void bin_gemm(const int* __restrict__ src,
                                                const int* __restrict__ dst,
                                                const int* __restrict__ partial,
                                                unsigned int* __restrict__ pairs,
                                                int* __restrict__ bbase,
                                                int E,
                                                const float* __restrict__ A,
                                                const unsigned short* __restrict__ Wt,
                                                const float* __restrict__ attn_l,
                                                unsigned short* __restrict__ ft16,
                                                float* __restrict__ el, int M,
                                                int ngb) {
    __shared__ unsigned short WtL[128 * 256];   // 64 KB (bin aliases 3 KB of it)

    if ((int)blockIdx.x >= ngb) {
        // ---------------- bin ----------------
        int* sc    = (int*)WtL;          // [0..255]
        int* basel = (int*)WtL + 256;    // [256..511]
        int* cnt   = (int*)WtL + 512;    // [512..767]
        const int t = threadIdx.x;
        const int b = blockIdx.x - ngb;
        const int chunk = (E + NCH - 1) / NCH;
        const int e0 = b * chunk;
        const int e1 = min(e0 + chunk, E);

        // preload this block's edges (static reg indices, predicated)
        int dreg[PRE], sreg[PRE];
        #pragma unroll
        for (int i = 0; i < PRE; ++i) {
            const int e = e0 + t + i * 256;
            const bool ok = e < e1;
            dreg[i] = ok ? dst[e] : 0;
            sreg[i] = ok ? src[e] : 0;
        }

        // base derivation: colsum over all rows, rowpref over rows < b
        int colsum = 0, rowpref = 0;
        {
            int bb = 0;
            #pragma unroll 8
            for (; bb < b; ++bb) {
                const int pv = partial[bb * 256 + t];
                colsum += pv;
                rowpref += pv;
            }
            #pragma unroll 8
            for (; bb < NCH; ++bb) colsum += partial[bb * 256 + t];
        }
        sc[t] = colsum;
        __syncthreads();
        #pragma unroll
        for (int d = 1; d < 256; d <<= 1) {
            int x = (t >= d) ? sc[t - d] : 0;
            __syncthreads();
            sc[t] += x;
            __syncthreads();
        }
        if (b == 0) {
            bbase[t] = sc[t] - colsum;
            if (t == 255) bbase[256] = sc[255];
        }
        basel[t] = (sc[t] - colsum) + rowpref;
        cnt[t] = 0;
        __syncthreads();

        // scatter (only LDS-atomic latency on the chain)
        #pragma unroll
        for (int i = 0; i < PRE; ++i) {
            const int e = e0 + t + i * 256;
            if (e < e1) {
                const int d = dreg[i];
                const int bk = d >> 8;
                const int o = atomicAdd(&cnt[bk], 1);
                pairs[basel[bk] + o] = (unsigned int)sreg[i] | ((unsigned int)(d & 255) << 16);
            }
        }
        for (int e = e0 + t + PRE * 256; e < e1; e += 256) {   // tail (empty normally)
            const int d = dst[e];
            const int bk = d >> 8;
            const int o = atomicAdd(&cnt[bk], 1);
            pairs[basel[bk] + o] = (unsigned int)src[e] | ((unsigned int)(d & 255) << 16);
        }
        return;
    }

    // ---------------- gemm_el ----------------
    const int gb   = blockIdx.x;
    const int wave = threadIdx.x >> 6;
    const int lane = threadIdx.x & 63;
    const int quad = lane >> 4;
    const int mc   = lane & 15;
    const int row_base = gb * 64 + wave * 16;

    for (int i = threadIdx.x; i < 4096; i += 256) {
        const int n = i >> 5, c = i & 31;
        const int cs = (c + n) & 31;
        *(uint4*)(WtL + n * 256 + cs * 8) = *(const uint4*)(Wt + n * 256 + c * 8);
    }

    float al[8];
    #pragma unroll
    for (int t = 0; t < 8; ++t) al[t] = attn_l[(t >> 1) * 32 + (t & 1) * 16 + mc];

    const int rowA = min(row_base + mc, M - 1);
    const float* arow = A + (size_t)rowA * IN_FEATS;

    float4 a[8][2];
    #pragma unroll
    for (int kk = 0; kk < 8; ++kk) {
        a[kk][0] = *(const float4*)(arow + kk * 32 + quad * 8);
        a[kk][1] = *(const float4*)(arow + kk * 32 + quad * 8 + 4);
    }

    f32x4 acc[8];
    #pragma unroll
    for (int t = 0; t < 8; ++t) acc[t] = (f32x4){0.f, 0.f, 0.f, 0.f};

    __syncthreads();

    #pragma unroll
    for (int kk = 0; kk < 8; ++kk) {
        short8 af;
        af[0] = (short)f2bf(a[kk][0].x); af[1] = (short)f2bf(a[kk][0].y);
        af[2] = (short)f2bf(a[kk][0].z); af[3] = (short)f2bf(a[kk][0].w);
        af[4] = (short)f2bf(a[kk][1].x); af[5] = (short)f2bf(a[kk][1].y);
        af[6] = (short)f2bf(a[kk][1].z); af[7] = (short)f2bf(a[kk][1].w);
        #pragma unroll
        for (int t = 0; t < 8; ++t) {
            const int n = t * 16 + mc;
            const int c = ((kk << 2) + quad + n) & 31;
            const short8 bf = *(const short8*)(WtL + n * 256 + c * 8);
            acc[t] = __builtin_amdgcn_mfma_f32_16x16x32_bf16(af, bf, acc[t], 0, 0, 0);
        }
    }

    float elp[4][4];
    #pragma unroll
    for (int v = 0; v < 4; ++v)
        #pragma unroll
        for (int h = 0; h < 4; ++h) elp[v][h] = 0.f;
    #pragma unroll
    for (int v = 0; v < 4; ++v)
        #pragma unroll
        for (int t = 0; t < 8; ++t) elp[v][t >> 1] += acc[t][v] * al[t];
    #pragma unroll
    for (int v = 0; v < 4; ++v)
        #pragma unroll
        for (int h = 0; h < 4; ++h) {
            #pragma unroll
            for (int d = 1; d < 16; d <<= 1)
                elp[v][h] += __shfl_xor(elp[v][h], d, 64);
        }

    // el store (registers only, before LDS reuse)
    #pragma unroll
    for (int v = 0; v < 4; ++v) {
        const int rg = row_base + quad * 4 + v;
        if (rg < M && mc < 4) {
            float ev = (mc == 0) ? elp[v][0] : (mc == 1) ? elp[v][1]
                     : (mc == 2) ? elp[v][2] : elp[v][3];
            el[(size_t)rg * 4 + mc] = ev;
        }
    }

    __syncthreads();   // all waves done reading WtL -> safe to reuse as bounce
    #pragma unroll
    for (int v = 0; v < 4; ++v) {
        const int lr = wave * 16 + quad * 4 + v;
        #pragma unroll
        for (int t = 0; t < 8; ++t)
            WtL[lr * BSTRIDE + t * 16 + mc] = f2bf(acc[t][v]);
    }
    __syncthreads();
    const int rows_in_blk = min(64, M - gb * 64);
    for (int i = threadIdx.x; i < 64 * 16; i += 256) {   // 16B segs
        const int lr = i >> 4, seg = i & 15;
        if (lr < rows_in_blk)
            *(uint4*)(ft16 + (size_t)(gb * 64 + lr) * NHF + seg * 8) =
                *(const uint4*)(WtL + lr * BSTRIDE + seg * 8);
    }
}

// er_fine: blocks 0..nb-1 = fine CSR per bucket (2KB LDS, cheap); blocks nb..
// = compute_er (one wave per dst row, no LDS). csr stored as u16 (src<65536).
__global__ __launch_bounds__(256) void er_fine(const float* __restrict__ hdst,
                                               const float* __restrict__ v,
                                               float* __restrict__ er, int M,
                                               const unsigned int* __restrict__ pairs,
                                               const int* __restrict__ bbase,
                                               int* __restrict__ off,
                                               unsigned short* __restrict__ csr16,
                                               int nb, int n_dst, int E) {
    __shared__ int cnt[256];
    __shared__ int cur[256];

    if (blockIdx.x < (unsigned)nb) {
        const int t = threadIdx.x;
        const int b = blockIdx.x;
        const int p0 = bbase[b], p1 = bbase[b + 1];
        cnt[t] = 0;
        __syncthreads();
        for (int p = p0 + t; p < p1; p += 256)
            atomicAdd(&cnt[pairs[p] >> 16], 1);
        __syncthreads();
        int vv = cnt[t];
        cur[t] = vv;
        __syncthreads();
        #pragma unroll
        for (int d = 1; d < 256; d <<= 1) {
            int x = (t >= d) ? cur[t - d] : 0;
            __syncthreads();
            cur[t] += x;
            __syncthreads();
        }
        int ex = cur[t] - vv;
        int node = b * 256 + t;
        if (node < n_dst) off[node] = p0 + ex;
        if (b == 0 && t == 0) off[n_dst] = E;
        __syncthreads();
        cur[t] = ex;
        __syncthreads();
        for (int p = p0 + t; p < p1; p += 256) {
            unsigned int pr = pairs[p];
            int o = atomicAdd(&cur[pr >> 16], 1);
            csr16[p0 + o] = (unsigned short)(pr & 0xffffu);
        }
        return;
    }

    // ---- compute_er ----
    int wid  = ((blockIdx.x - nb) * 256 + threadIdx.x) >> 6;
    int lane = threadIdx.x & 63;
    if (wid >= M) return;
    const float4 x = *(const float4*)(hdst + (size_t)wid * IN_FEATS + lane * 4);
    const float4* vp = (const float4*)(v + (size_t)lane * 16);
    float4 v0 = vp[0], v1 = vp[1], v2 = vp[2], v3 = vp[3];
    float a0 = x.x * v0.x + x.y * v1.x + x.z * v2.x + x.w * v3.x;
    float a1 = x.x * v0.y + x.y * v1.y + x.z * v2.y + x.w * v3.y;
    float a2 = x.x * v0.z + x.y * v1.z + x.z * v2.z + x.w * v3.z;
    float a3 = x.x * v0.w + x.y * v1.w + x.z * v2.w + x.w * v3.w;
    #pragma unroll
    for (int m = 32; m >= 1; m >>= 1) {
        a0 += __shfl_xor(a0, m, 64);
        a1 += __shfl_xor(a1, m, 64);
        a2 += __shfl_xor(a2, m, 64);
        a3 += __shfl_xor(a3, m, 64);
    }
    if (lane == 0) *(float4*)(er + (size_t)wid * 4) = make_float4(a0, a1, a2, a3);
}

// TWO dst nodes per wave (32 lanes each; lane owns cols 4*hl..4*hl+3).
// Per half-wave: up to 32 csr entries preloaded with ONE coalesced u16 load,
// broadcast via __shfl(width=32). 8-edge chunks, 2-stage software pipeline.
__global__ __launch_bounds__(256) void agg_pull(const int* __restrict__ off,
                                                const unsigned short* __restrict__ csr16,
                                                const float* __restrict__ el,
                                                const float* __restrict__ er,
                                                const uint2* __restrict__ ftp,
                                                float* __restrict__ out, int n_dst) {
    const int wid  = (blockIdx.x * blockDim.x + threadIdx.x) >> 6;
    const int lane = threadIdx.x & 63;
    const int half = lane >> 5;
    const int hl   = lane & 31;
    const int node = wid * 2 + half;
    const bool valid = node < n_dst;
    const int nc = valid ? node : 0;
    const int h  = hl >> 3;                       // head = (4*hl)/32
    const float er_h = er[nc * 4 + h];
    const int start = off[nc];
    const int end   = valid ? off[nc + 1] : start;
    const int deg   = end - start;
    const int last  = max(end - 1, 0);

    const int sl = (int)csr16[min(start + hl, last)];

    const int mdeg  = max(deg, __shfl_xor(deg, 32, 64));
    const int iters = (min(mdeg, 32) + 7) >> 3;

    float a0 = 0.f, a1 = 0.f, a2 = 0.f, a3 = 0.f, sw = 0.f;

    float e[8]; uint2 q[8];
    #pragma unroll
    for (int j = 0; j < 8; ++j) {
        const int s = __shfl(sl, j, 32);
        e[j] = el[s * 4 + h];
        q[j] = ftp[s * 32 + hl];
    }

    for (int i = 0; i < iters; ++i) {
        float f[8]; uint2 r[8];
        const int jn = (i + 1) << 3;
        #pragma unroll
        for (int j = 0; j < 8; ++j) {
            const int s = __shfl(sl, min(jn + j, 31), 32);
            f[j] = el[s * 4 + h];
            r[j] = ftp[s * 32 + hl];
        }

        const int kb = start + (i << 3);
        #pragma unroll
        for (int j = 0; j < 8; ++j) {
            float x = e[j] + er_h;
            x = fmaxf(x, 0.2f * x);
            const float w = (kb + j < end) ? __expf(x) : 0.f;
            sw += w;
            a0 = fmaf(bfhi2f(q[j].x << 16),          w, a0);
            a1 = fmaf(bfhi2f(q[j].x & 0xffff0000u),  w, a1);
            a2 = fmaf(bfhi2f(q[j].y << 16),          w, a2);
            a3 = fmaf(bfhi2f(q[j].y & 0xffff0000u),  w, a3);
        }

        #pragma unroll
        for (int j = 0; j < 8; ++j) { e[j] = f[j]; q[j] = r[j]; }
    }

    for (int k = start + 32; k < end; ++k) {
        const int s = (int)csr16[k];
        float x = el[s * 4 + h] + er_h;
        x = fmaxf(x, 0.2f * x);
        const float w = __expf(x);
        const uint2 qq = ftp[s * 32 + hl];
        sw += w;
        a0 = fmaf(bfhi2f(qq.x << 16),         w, a0);
        a1 = fmaf(bfhi2f(qq.x & 0xffff0000u), w, a1);
        a2 = fmaf(bfhi2f(qq.y << 16),         w, a2);
        a3 = fmaf(bfhi2f(qq.y & 0xffff0000u), w, a3);
    }

    if (valid) {
        const float inv = (deg > 0) ? 1.f / sw : 0.f;
        float4 r;
        r.x = a0 * inv; r.y = a1 * inv; r.z = a2 * inv; r.w = a3 * inv;
        *(float4*)(out + (size_t)node * NHF + hl * 4) = r;
    }
}

extern "C" void kernel_launch(void* const* d_in, const int* in_sizes, int n_in,
                              void* d_out, int out_size, void* d_ws, size_t ws_size,
                              hipStream_t stream) {
    const float* h_src  = (const float*)d_in[0];
    const float* h_dst  = (const float*)d_in[1];
    const float* W      = (const float*)d_in[2];
    const float* attn_l = (const float*)d_in[3];
    const float* attn_r = (const float*)d_in[4];
    const int* src_idx  = (const int*)d_in[5];
    const int* dst_idx  = (const int*)d_in[6];

    const int n_src = in_sizes[0] / IN_FEATS;   // 50000
    const int n_dst = in_sizes[1] / IN_FEATS;   // 50000
    const int E     = in_sizes[5];              // 800000

    const int nb = (n_dst + 255) >> 8;          // 196 buckets (<=256)

    // workspace layout
    char* ws = (char*)d_ws;
    size_t o = 0;
    float* v       = (float*)(ws + o); o += 4096;
    float* el      = (float*)(ws + o); o += (size_t)n_src * 4 * sizeof(float);
    float* er      = (float*)(ws + o); o += (size_t)n_dst * 4 * sizeof(float);
    int*   off     = (int*)(ws + o);   o += ((size_t)n_dst + 16) * sizeof(int);
    int*   bbase   = (int*)(ws + o);   o += 260 * sizeof(int);
    int*   partial = (int*)(ws + o);   o += (size_t)NCH * 256 * sizeof(int);
    unsigned short* Wt = (unsigned short*)(ws + o); o += (size_t)NHF * IN_FEATS * sizeof(unsigned short);
    unsigned short* csr16 = (unsigned short*)(ws + o); o += (((size_t)E * 2 + 15) & ~15ull);
    unsigned int* pairs = (unsigned int*)(ws + o); o += (size_t)E * sizeof(unsigned int);
    unsigned short* ft16 = (unsigned short*)(ws + o); o += (size_t)n_src * NHF * sizeof(unsigned short);

    float* out = (float*)d_out;

    const int ngb = (n_src + 63) / 64;          // gemm blocks FIRST

    prep_hist<<<129 + NCH, 256, 0, stream>>>(W, attn_r, dst_idx, v, Wt, partial, E);
    bin_gemm<<<ngb + NCH, 256, 0, stream>>>(src_idx, dst_idx, partial,
                                            pairs, bbase, E,
                                            h_src, Wt, attn_l, ft16, el, n_src, ngb);
    {
        const int er_blocks = (n_dst * 64 + 255) / 256;  // 4 rows/block
        er_fine<<<nb + er_blocks, 256, 0, stream>>>(h_dst, v, er, n_dst, pairs,
                                                    bbase, off, csr16, nb, n_dst, E);
    }
    {
        const int nwave = (n_dst + 1) >> 1;          // 2 nodes per wave
        agg_pull<<<(nwave + 3) / 4, 256, 0, stream>>>(off, csr16, el, er,
                                                      (const uint2*)ft16, out, n_dst);
    }
}

// Round 11
// 213.583 us; speedup vs baseline: 1.0758x; 1.0267x over previous
//
#include <hip/hip_runtime.h>

#define IN_FEATS 256
#define OUT_FEATS 32
#define NUM_HEADS 4
#define NHF 128   // NUM_HEADS*OUT_FEATS

#define NCH 256   // edge chunks for hist/bin; chunk<=3328 covered by 13-reg preload
#define PRE 13    // preload regs: PRE*256 >= chunk

typedef __attribute__((ext_vector_type(8))) short short8;
typedef __attribute__((ext_vector_type(4))) float f32x4;

__device__ inline unsigned short f2bf(float f) {
    unsigned int u = __builtin_bit_cast(unsigned int, f);
    u = (u + 0x7fff + ((u >> 16) & 1)) >> 16;   // RNE
    return (unsigned short)u;
}
__device__ inline float bfhi2f(unsigned int packed_hi) {   // bits already in [31:16]
    return __builtin_bit_cast(float, packed_hi);
}

// prep_hist: blocks 0..127 transpose W -> Wt bf16 [128][256]; block 128 computes
// v[k*4+h]; blocks 129.. accumulate the dst-bucket histogram directly into
// global bcnt[256] (pre-zeroed by a 2KB memset) -- no partial array.
__global__ __launch_bounds__(256) void prep_hist(const float* __restrict__ W,
                                                 const float* __restrict__ attn_r,
                                                 const int* __restrict__ dst,
                                                 float* __restrict__ v,
                                                 unsigned short* __restrict__ Wt,
                                                 int* __restrict__ bcnt,
                                                 int E) {
    const int t = threadIdx.x;
    const int b = blockIdx.x;
    if (b < 128) {
        Wt[b * 256 + t] = f2bf(W[(size_t)t * NHF + b]);
    } else if (b == 128) {
        for (int p = t; p < IN_FEATS * NUM_HEADS; p += 256) {
            int k = p >> 2, h = p & 3;
            const float* wr = W + (size_t)k * NHF + h * OUT_FEATS;
            const float* ar = attn_r + h * OUT_FEATS;
            float s = 0.f;
            #pragma unroll
            for (int f = 0; f < OUT_FEATS; ++f) s += wr[f] * ar[f];
            v[p] = s;
        }
    } else {
        __shared__ int cnt[256];
        const int hb = b - 129;
        const int chunk = (E + NCH - 1) / NCH;
        const int e0 = hb * chunk;
        const int e1 = min(e0 + chunk, E);
        cnt[t] = 0;
        __syncthreads();
        for (int e = e0 + t; e < e1; e += 256)
            atomicAdd(&cnt[dst[e] >> 8], 1);
        __syncthreads();
        int c = cnt[t];
        if (c) atomicAdd(&bcnt[t], c);
    }
}

// bin_gemm v4 (R8 ordering: gemm FIRST, bin behind). Bin now derives bbase
// from global bcnt (1 load + LDS scan) and reserves its run with ONE global
// atomicAdd per bucket -- the O(NCH) partial sweep is gone. Pair order within
// a bucket becomes non-deterministic; fine_csr re-counts so correctness holds.
#define BSTRIDE 136   // bf16 elems; 272 B rows: 16B-aligned, 4-bank shift/row
__global__ __launch_bounds__(256) void bin_gemm(const int* __restrict__ src,
                                                const int* __restrict__ dst,
                                                const int* __restrict__ bcnt,
                                                int* __restrict__ bcursor,
                                                unsigned int* __restrict__ pairs,
                                                int* __restrict__ bbase,
                                                int E,
                                                const float* __restrict__ A,
                                                const unsigned short* __restrict__ Wt,
                                                const float* __restrict__ attn_l,
                                                unsigned short* __restrict__ ft16,
                                                float* __restrict__ el, int M,
                                                int ngb) {
    __shared__ unsigned short WtL[128 * 256];   // 64 KB (bin aliases 3 KB of it)

    if ((int)blockIdx.x >= ngb) {
        // ---------------- bin ----------------
        int* sc    = (int*)WtL;          // [0..255]
        int* basel = (int*)WtL + 256;    // [256..511]
        int* cnt   = (int*)WtL + 512;    // [512..767]
        const int t = threadIdx.x;
        const int b = blockIdx.x - ngb;
        const int chunk = (E + NCH - 1) / NCH;
        const int e0 = b * chunk;
        const int e1 = min(e0 + chunk, E);

        // preload this block's edges (static reg indices, predicated)
        int dreg[PRE], sreg[PRE];
        #pragma unroll
        for (int i = 0; i < PRE; ++i) {
            const int e = e0 + t + i * 256;
            const bool ok = e < e1;
            dreg[i] = ok ? dst[e] : 0;
            sreg[i] = ok ? src[e] : 0;
        }

        // local histogram of this chunk
        cnt[t] = 0;
        __syncthreads();
        #pragma unroll
        for (int i = 0; i < PRE; ++i) {
            const int e = e0 + t + i * 256;
            if (e < e1) atomicAdd(&cnt[dreg[i] >> 8], 1);
        }
        for (int e = e0 + t + PRE * 256; e < e1; e += 256)   // tail (empty normally)
            atomicAdd(&cnt[dst[e] >> 8], 1);
        __syncthreads();
        const int myc = cnt[t];

        // bbase from global bcnt: 1 load + LDS inclusive scan
        const int bv = bcnt[t];
        sc[t] = bv;
        __syncthreads();
        #pragma unroll
        for (int d = 1; d < 256; d <<= 1) {
            int x = (t >= d) ? sc[t - d] : 0;
            __syncthreads();
            sc[t] += x;
            __syncthreads();
        }
        const int bb_t = sc[t] - bv;   // exclusive prefix = bucket base
        if (b == 0) {
            bbase[t] = bb_t;
            if (t == 255) bbase[256] = sc[255];
        }

        // reserve a contiguous run per non-empty bucket (order nondeterministic)
        basel[t] = myc ? (bb_t + atomicAdd(&bcursor[t], myc)) : 0;
        cnt[t] = 0;
        __syncthreads();

        // scatter (only LDS-atomic latency on the chain)
        #pragma unroll
        for (int i = 0; i < PRE; ++i) {
            const int e = e0 + t + i * 256;
            if (e < e1) {
                const int d = dreg[i];
                const int bk = d >> 8;
                const int o = atomicAdd(&cnt[bk], 1);
                pairs[basel[bk] + o] = (unsigned int)sreg[i] | ((unsigned int)(d & 255) << 16);
            }
        }
        for (int e = e0 + t + PRE * 256; e < e1; e += 256) {   // tail (empty normally)
            const int d = dst[e];
            const int bk = d >> 8;
            const int o = atomicAdd(&cnt[bk], 1);
            pairs[basel[bk] + o] = (unsigned int)src[e] | ((unsigned int)(d & 255) << 16);
        }
        return;
    }

    // ---------------- gemm_el ----------------
    const int gb   = blockIdx.x;
    const int wave = threadIdx.x >> 6;
    const int lane = threadIdx.x & 63;
    const int quad = lane >> 4;
    const int mc   = lane & 15;
    const int row_base = gb * 64 + wave * 16;

    for (int i = threadIdx.x; i < 4096; i += 256) {
        const int n = i >> 5, c = i & 31;
        const int cs = (c + n) & 31;
        *(uint4*)(WtL + n * 256 + cs * 8) = *(const uint4*)(Wt + n * 256 + c * 8);
    }

    float al[8];
    #pragma unroll
    for (int t = 0; t < 8; ++t) al[t] = attn_l[(t >> 1) * 32 + (t & 1) * 16 + mc];

    const int rowA = min(row_base + mc, M - 1);
    const float* arow = A + (size_t)rowA * IN_FEATS;

    float4 a[8][2];
    #pragma unroll
    for (int kk = 0; kk < 8; ++kk) {
        a[kk][0] = *(const float4*)(arow + kk * 32 + quad * 8);
        a[kk][1] = *(const float4*)(arow + kk * 32 + quad * 8 + 4);
    }

    f32x4 acc[8];
    #pragma unroll
    for (int t = 0; t < 8; ++t) acc[t] = (f32x4){0.f, 0.f, 0.f, 0.f};

    __syncthreads();

    #pragma unroll
    for (int kk = 0; kk < 8; ++kk) {
        short8 af;
        af[0] = (short)f2bf(a[kk][0].x); af[1] = (short)f2bf(a[kk][0].y);
        af[2] = (short)f2bf(a[kk][0].z); af[3] = (short)f2bf(a[kk][0].w);
        af[4] = (short)f2bf(a[kk][1].x); af[5] = (short)f2bf(a[kk][1].y);
        af[6] = (short)f2bf(a[kk][1].z); af[7] = (short)f2bf(a[kk][1].w);
        #pragma unroll
        for (int t = 0; t < 8; ++t) {
            const int n = t * 16 + mc;
            const int c = ((kk << 2) + quad + n) & 31;
            const short8 bf = *(const short8*)(WtL + n * 256 + c * 8);
            acc[t] = __builtin_amdgcn_mfma_f32_16x16x32_bf16(af, bf, acc[t], 0, 0, 0);
        }
    }

    float elp[4][4];
    #pragma unroll
    for (int v = 0; v < 4; ++v)
        #pragma unroll
        for (int h = 0; h < 4; ++h) elp[v][h] = 0.f;
    #pragma unroll
    for (int v = 0; v < 4; ++v)
        #pragma unroll
        for (int t = 0; t < 8; ++t) elp[v][t >> 1] += acc[t][v] * al[t];
    #pragma unroll
    for (int v = 0; v < 4; ++v)
        #pragma unroll
        for (int h = 0; h < 4; ++h) {
            #pragma unroll
            for (int d = 1; d < 16; d <<= 1)
                elp[v][h] += __shfl_xor(elp[v][h], d, 64);
        }

    // el store (registers only, before LDS reuse)
    #pragma unroll
    for (int v = 0; v < 4; ++v) {
        const int rg = row_base + quad * 4 + v;
        if (rg < M && mc < 4) {
            float ev = (mc == 0) ? elp[v][0] : (mc == 1) ? elp[v][1]
                     : (mc == 2) ? elp[v][2] : elp[v][3];
            el[(size_t)rg * 4 + mc] = ev;
        }
    }

    __syncthreads();   // all waves done reading WtL -> safe to reuse as bounce
    #pragma unroll
    for (int v = 0; v < 4; ++v) {
        const int lr = wave * 16 + quad * 4 + v;
        #pragma unroll
        for (int t = 0; t < 8; ++t)
            WtL[lr * BSTRIDE + t * 16 + mc] = f2bf(acc[t][v]);
    }
    __syncthreads();
    const int rows_in_blk = min(64, M - gb * 64);
    for (int i = threadIdx.x; i < 64 * 16; i += 256) {   // 16B segs
        const int lr = i >> 4, seg = i & 15;
        if (lr < rows_in_blk)
            *(uint4*)(ft16 + (size_t)(gb * 64 + lr) * NHF + seg * 8) =
                *(const uint4*)(WtL + lr * BSTRIDE + seg * 8);
    }
}

// er_fine: blocks 0..nb-1 = fine CSR per bucket (2KB LDS, cheap); blocks nb..
// = compute_er (one wave per dst row, no LDS). csr stored as u16 (src<65536).
__global__ __launch_bounds__(256) void er_fine(const float* __restrict__ hdst,
                                               const float* __restrict__ v,
                                               float* __restrict__ er, int M,
                                               const unsigned int* __restrict__ pairs,
                                               const int* __restrict__ bbase,
                                               int* __restrict__ off,
                                               unsigned short* __restrict__ csr16,
                                               int nb, int n_dst, int E) {
    __shared__ int cnt[256];
    __shared__ int cur[256];

    if (blockIdx.x < (unsigned)nb) {
        const int t = threadIdx.x;
        const int b = blockIdx.x;
        const int p0 = bbase[b], p1 = bbase[b + 1];
        cnt[t] = 0;
        __syncthreads();
        for (int p = p0 + t; p < p1; p += 256)
            atomicAdd(&cnt[pairs[p] >> 16], 1);
        __syncthreads();
        int vv = cnt[t];
        cur[t] = vv;
        __syncthreads();
        #pragma unroll
        for (int d = 1; d < 256; d <<= 1) {
            int x = (t >= d) ? cur[t - d] : 0;
            __syncthreads();
            cur[t] += x;
            __syncthreads();
        }
        int ex = cur[t] - vv;
        int node = b * 256 + t;
        if (node < n_dst) off[node] = p0 + ex;
        if (b == 0 && t == 0) off[n_dst] = E;
        __syncthreads();
        cur[t] = ex;
        __syncthreads();
        for (int p = p0 + t; p < p1; p += 256) {
            unsigned int pr = pairs[p];
            int o = atomicAdd(&cur[pr >> 16], 1);
            csr16[p0 + o] = (unsigned short)(pr & 0xffffu);
        }
        return;
    }

    // ---- compute_er ----
    int wid  = ((blockIdx.x - nb) * 256 + threadIdx.x) >> 6;
    int lane = threadIdx.x & 63;
    if (wid >= M) return;
    const float4 x = *(const float4*)(hdst + (size_t)wid * IN_FEATS + lane * 4);
    const float4* vp = (const float4*)(v + (size_t)lane * 16);
    float4 v0 = vp[0], v1 = vp[1], v2 = vp[2], v3 = vp[3];
    float a0 = x.x * v0.x + x.y * v1.x + x.z * v2.x + x.w * v3.x;
    float a1 = x.x * v0.y + x.y * v1.y + x.z * v2.y + x.w * v3.y;
    float a2 = x.x * v0.z + x.y * v1.z + x.z * v2.z + x.w * v3.z;
    float a3 = x.x * v0.w + x.y * v1.w + x.z * v2.w + x.w * v3.w;
    #pragma unroll
    for (int m = 32; m >= 1; m >>= 1) {
        a0 += __shfl_xor(a0, m, 64);
        a1 += __shfl_xor(a1, m, 64);
        a2 += __shfl_xor(a2, m, 64);
        a3 += __shfl_xor(a3, m, 64);
    }
    if (lane == 0) *(float4*)(er + (size_t)wid * 4) = make_float4(a0, a1, a2, a3);
}

// TWO dst nodes per wave (32 lanes each; lane owns cols 4*hl..4*hl+3).
// Per half-wave: up to 32 csr entries preloaded with ONE coalesced u16 load,
// broadcast via __shfl(width=32). 8-edge chunks, 2-stage software pipeline.
__global__ __launch_bounds__(256) void agg_pull(const int* __restrict__ off,
                                                const unsigned short* __restrict__ csr16,
                                                const float* __restrict__ el,
                                                const float* __restrict__ er,
                                                const uint2* __restrict__ ftp,
                                                float* __restrict__ out, int n_dst) {
    const int wid  = (blockIdx.x * blockDim.x + threadIdx.x) >> 6;
    const int lane = threadIdx.x & 63;
    const int half = lane >> 5;
    const int hl   = lane & 31;
    const int node = wid * 2 + half;
    const bool valid = node < n_dst;
    const int nc = valid ? node : 0;
    const int h  = hl >> 3;                       // head = (4*hl)/32
    const float er_h = er[nc * 4 + h];
    const int start = off[nc];
    const int end   = valid ? off[nc + 1] : start;
    const int deg   = end - start;
    const int last  = max(end - 1, 0);

    const int sl = (int)csr16[min(start + hl, last)];

    const int mdeg  = max(deg, __shfl_xor(deg, 32, 64));
    const int iters = (min(mdeg, 32) + 7) >> 3;

    float a0 = 0.f, a1 = 0.f, a2 = 0.f, a3 = 0.f, sw = 0.f;

    float e[8]; uint2 q[8];
    #pragma unroll
    for (int j = 0; j < 8; ++j) {
        const int s = __shfl(sl, j, 32);
        e[j] = el[s * 4 + h];
        q[j] = ftp[s * 32 + hl];
    }

    for (int i = 0; i < iters; ++i) {
        float f[8]; uint2 r[8];
        const int jn = (i + 1) << 3;
        #pragma unroll
        for (int j = 0; j < 8; ++j) {
            const int s = __shfl(sl, min(jn + j, 31), 32);
            f[j] = el[s * 4 + h];
            r[j] = ftp[s * 32 + hl];
        }

        const int kb = start + (i << 3);
        #pragma unroll
        for (int j = 0; j < 8; ++j) {
            float x = e[j] + er_h;
            x = fmaxf(x, 0.2f * x);
            const float w = (kb + j < end) ? __expf(x) : 0.f;
            sw += w;
            a0 = fmaf(bfhi2f(q[j].x << 16),          w, a0);
            a1 = fmaf(bfhi2f(q[j].x & 0xffff0000u),  w, a1);
            a2 = fmaf(bfhi2f(q[j].y << 16),          w, a2);
            a3 = fmaf(bfhi2f(q[j].y & 0xffff0000u),  w, a3);
        }

        #pragma unroll
        for (int j = 0; j < 8; ++j) { e[j] = f[j]; q[j] = r[j]; }
    }

    for (int k = start + 32; k < end; ++k) {
        const int s = (int)csr16[k];
        float x = el[s * 4 + h] + er_h;
        x = fmaxf(x, 0.2f * x);
        const float w = __expf(x);
        const uint2 qq = ftp[s * 32 + hl];
        sw += w;
        a0 = fmaf(bfhi2f(qq.x << 16),         w, a0);
        a1 = fmaf(bfhi2f(qq.x & 0xffff0000u), w, a1);
        a2 = fmaf(bfhi2f(qq.y << 16),         w, a2);
        a3 = fmaf(bfhi2f(qq.y & 0xffff0000u), w, a3);
    }

    if (valid) {
        const float inv = (deg > 0) ? 1.f / sw : 0.f;
        float4 r;
        r.x = a0 * inv; r.y = a1 * inv; r.z = a2 * inv; r.w = a3 * inv;
        *(float4*)(out + (size_t)node * NHF + hl * 4) = r;
    }
}

extern "C" void kernel_launch(void* const* d_in, const int* in_sizes, int n_in,
                              void* d_out, int out_size, void* d_ws, size_t ws_size,
                              hipStream_t stream) {
    const float* h_src  = (const float*)d_in[0];
    const float* h_dst  = (const float*)d_in[1];
    const float* W      = (const float*)d_in[2];
    const float* attn_l = (const float*)d_in[3];
    const float* attn_r = (const float*)d_in[4];
    const int* src_idx  = (const int*)d_in[5];
    const int* dst_idx  = (const int*)d_in[6];

    const int n_src = in_sizes[0] / IN_FEATS;   // 50000
    const int n_dst = in_sizes[1] / IN_FEATS;   // 50000
    const int E     = in_sizes[5];              // 800000

    const int nb = (n_dst + 255) >> 8;          // 196 buckets (<=256)

    // workspace layout
    char* ws = (char*)d_ws;
    size_t o = 0;
    float* v       = (float*)(ws + o); o += 4096;
    float* el      = (float*)(ws + o); o += (size_t)n_src * 4 * sizeof(float);
    float* er      = (float*)(ws + o); o += (size_t)n_dst * 4 * sizeof(float);
    int*   off     = (int*)(ws + o);   o += ((size_t)n_dst + 16) * sizeof(int);
    int*   bcnt    = (int*)(ws + o);   o += 256 * sizeof(int);
    int*   bcursor = (int*)(ws + o);   o += 256 * sizeof(int);
    int*   bbase   = (int*)(ws + o);   o += 260 * sizeof(int);
    unsigned short* Wt = (unsigned short*)(ws + o); o += (size_t)NHF * IN_FEATS * sizeof(unsigned short);
    unsigned short* csr16 = (unsigned short*)(ws + o); o += (((size_t)E * 2 + 15) & ~15ull);
    unsigned int* pairs = (unsigned int*)(ws + o); o += (size_t)E * sizeof(unsigned int);
    unsigned short* ft16 = (unsigned short*)(ws + o); o += (size_t)n_src * NHF * sizeof(unsigned short);

    float* out = (float*)d_out;

    const int ngb = (n_src + 63) / 64;          // gemm blocks FIRST

    (void)hipMemsetAsync(bcnt, 0, 512 * sizeof(int), stream);   // bcnt + bcursor

    prep_hist<<<129 + NCH, 256, 0, stream>>>(W, attn_r, dst_idx, v, Wt, bcnt, E);
    bin_gemm<<<ngb + NCH, 256, 0, stream>>>(src_idx, dst_idx, bcnt, bcursor,
                                            pairs, bbase, E,
                                            h_src, Wt, attn_l, ft16, el, n_src, ngb);
    {
        const int er_blocks = (n_dst * 64 + 255) / 256;  // 4 rows/block
        er_fine<<<nb + er_blocks, 256, 0, stream>>>(h_dst, v, er, n_dst, pairs,
                                                    bbase, off, csr16, nb, n_dst, E);
    }
    {
        const int nwave = (n_dst + 1) >> 1;          // 2 nodes per wave
        agg_pull<<<(nwave + 3) / 4, 256, 0, stream>>>(off, csr16, el, er,
                                                      (const uint2*)ft16, out, n_dst);
    }
}